// Round 9
// baseline (192.884 us; speedup 1.0000x reference)
//
#include <hip/hip_runtime.h>

// ---------------------------------------------------------------------------
// MultiHeadAttention: b=2, n=2048, EMB=1024, heads=16, head_dim=64
// R9: (1) gemm_qkv back to __launch_bounds__(256,3) (R8's (256,4) regressed);
//     (2) gemm_out re-tiled 128x64, grid (16,32)=512 blocks (2 blk/CU, 8 w/CU);
//     (3) attn: 256-thr blocks, q-tile 64, grid (bh=32, qt=32)=1024 blocks ->
//         4 blocks/CU: same 16 waves/CU but barriers hold only 4 waves each,
//         so the other 12 hide the staging drain. XCD swizzle kept (bh = x).
// ---------------------------------------------------------------------------

typedef short short8  __attribute__((ext_vector_type(8)));
typedef float floatx4 __attribute__((ext_vector_type(4)));

#define SEQ   2048
#define BATCH 2
#define NH    16
#define HD    64
#define EMB   1024

// softmax_e(E/32) == softmax_2(E * log2e/32); folded into Q.
#define QSCALE 0.045084220027780106f

__device__ __forceinline__ unsigned short f32_bf16(float f) {
    unsigned int u = __float_as_uint(f);
    u += 0x7FFF + ((u >> 16) & 1);      // round-to-nearest-even
    return (unsigned short)(u >> 16);
}

// pack two floats to bf16x2 (round-to-nearest, ties-away): 2 adds + 1 perm
__device__ __forceinline__ unsigned int pk_bf16(float lo, float hi) {
    return __builtin_amdgcn_perm(__float_as_uint(hi) + 0x8000u,
                                 __float_as_uint(lo) + 0x8000u, 0x07060302u);
}

// async global->LDS, 16B per lane; LDS dest = wave-uniform base + lane*16
__device__ __forceinline__ void gl_lds16(const unsigned short* g,
                                         unsigned short* l) {
    __builtin_amdgcn_global_load_lds(
        (const __attribute__((address_space(1))) unsigned int*)g,
        (__attribute__((address_space(3))) unsigned int*)l, 16, 0, 0);
}

// ---------------------------------------------------------------------------
// fp32 -> bf16 conversion for x, Wq, Wk, Wv, Wo (laid contiguously at ws+0)
// ---------------------------------------------------------------------------
__global__ __launch_bounds__(256) void convert_all(
        const float* __restrict__ x,  const float* __restrict__ wq,
        const float* __restrict__ wk, const float* __restrict__ wv,
        const float* __restrict__ wo, unsigned short* __restrict__ dst) {
    int i = (blockIdx.x * 256 + threadIdx.x) * 4;
    const float* src; int off;
    if      (i < 4194304) { src = x;  off = 0; }
    else if (i < 5242880) { src = wq; off = 4194304; }
    else if (i < 6291456) { src = wk; off = 5242880; }
    else if (i < 7340032) { src = wv; off = 6291456; }
    else                  { src = wo; off = 7340032; }
    float4 v = *(const float4*)(src + (i - off));
    uint2 o;
    o.x = pk_bf16(v.x, v.y);
    o.y = pk_bf16(v.z, v.w);
    *(uint2*)(dst + i) = o;
}

// ---------------------------------------------------------------------------
// QKV GEMM: C[4096,1024] = A[4096,1024] * B[1024,1024]^T + bias
// 256 thr / 4 waves, 128x128 tile, global_load_lds + XOR-chunk swizzle.
// MODE 0: bf16 | MODE 1: bf16*QSCALE (Q) | MODE 2: bf16 -> VT scatter (V)
// ---------------------------------------------------------------------------
template <int MODE>
__device__ __forceinline__ void gemm_bt_core(
        unsigned short (* __restrict__ sA)[64],
        unsigned short (* __restrict__ sB)[64],
        const unsigned short* __restrict__ A,
        const unsigned short* __restrict__ B,
        const float* __restrict__ bias,
        unsigned short* __restrict__ outb) {
    const int t    = threadIdx.x;
    const int wave = t >> 6, lane = t & 63;
    const int l15  = lane & 15, quad = lane >> 4;
    const int wm   = (wave >> 1) * 64, wn = (wave & 1) * 64;
    const int m0   = blockIdx.y * 128,  n0 = blockIdx.x * 128;
    const int srow = lane >> 3;                 // 0..7
    const int sch  = ((lane & 7) ^ srow) * 8;   // swizzled source chunk

    floatx4 acc[4][4] = {};

    for (int k0 = 0; k0 < EMB; k0 += 64) {
        for (int i = 0; i < 4; ++i) {
            int rr  = wave * 32 + i * 8;        // wave-uniform row base
            int row = rr + srow;
            gl_lds16(&A[(size_t)(m0 + row) * EMB + k0 + sch], &sA[0][0] + rr * 64);
            gl_lds16(&B[(size_t)(n0 + row) * EMB + k0 + sch], &sB[0][0] + rr * 64);
        }
        __syncthreads();
        for (int ks = 0; ks < 2; ++ks) {
            const int ch = (((ks * 4) + quad) ^ (l15 & 7)) * 8;
            short8 af[4], bf[4];
            for (int i = 0; i < 4; ++i)
                af[i] = *(const short8*)&sA[wm + i * 16 + l15][ch];
            for (int j = 0; j < 4; ++j)
                bf[j] = *(const short8*)&sB[wn + j * 16 + l15][ch];
            for (int i = 0; i < 4; ++i)
                for (int j = 0; j < 4; ++j)
                    acc[i][j] = __builtin_amdgcn_mfma_f32_16x16x32_bf16(
                        af[i], bf[j], acc[i][j], 0, 0, 0);
        }
        __syncthreads();
    }
    // C/D layout: col = lane&15, row = quad*4 + reg
    if (MODE == 2) {
        // V: write transposed VT[(b*16+h)*64 + d][seq]
        for (int i = 0; i < 4; ++i) {
            int row = m0 + wm + i * 16 + quad * 4;
            int bb  = row >> 11, seq = row & 2047;
            for (int j = 0; j < 4; ++j) {
                int col = n0 + wn + j * 16 + l15;
                float bv = bias[col];
                int vtrow = (bb * 16 + (col >> 6)) * 64 + (col & 63);
                uint2 pk;
                pk.x = pk_bf16(acc[i][j][0] + bv, acc[i][j][1] + bv);
                pk.y = pk_bf16(acc[i][j][2] + bv, acc[i][j][3] + bv);
                *(uint2*)&outb[(size_t)vtrow * SEQ + seq] = pk;
            }
        }
    } else {
        const float sc2 = (MODE == 1) ? QSCALE : 1.0f;
        for (int i = 0; i < 4; ++i) {
            int row = m0 + wm + i * 16 + quad * 4;
            for (int j = 0; j < 4; ++j) {
                int col = n0 + wn + j * 16 + l15;
                float bv = bias[col];
                for (int r = 0; r < 4; ++r) {
                    float v = (acc[i][j][r] + bv) * sc2;
                    outb[(size_t)(row + r) * EMB + col] = f32_bf16(v);
                }
            }
        }
    }
}

__global__ __launch_bounds__(256, 3) void gemm_qkv(
        const unsigned short* __restrict__ xb,
        const unsigned short* __restrict__ wq,
        const unsigned short* __restrict__ wk,
        const unsigned short* __restrict__ wv,
        const float* __restrict__ bq, const float* __restrict__ bk,
        const float* __restrict__ bv,
        unsigned short* __restrict__ Q, unsigned short* __restrict__ K,
        unsigned short* __restrict__ VT) {
    __shared__ unsigned short sA[128][64];
    __shared__ unsigned short sB[128][64];
    if      (blockIdx.z == 0) gemm_bt_core<1>(sA, sB, xb, wq, bq, Q);
    else if (blockIdx.z == 1) gemm_bt_core<0>(sA, sB, xb, wk, bk, K);
    else                      gemm_bt_core<2>(sA, sB, xb, wv, bv, VT);
}

// ---------------------------------------------------------------------------
// Output GEMM (fp32 out): 128x64 tile, 256 thr / 4 waves (wave = 32m x 64n),
// grid (16,32) = 512 blocks -> 2 blocks/CU, 8 waves/CU.
// ---------------------------------------------------------------------------
__global__ __launch_bounds__(256) void gemm_out(
        const unsigned short* __restrict__ A,
        const unsigned short* __restrict__ B,
        const float* __restrict__ bias, float* __restrict__ out) {
    __shared__ unsigned short sA[128][64];
    __shared__ unsigned short sB[64][64];
    const int t    = threadIdx.x;
    const int wave = t >> 6, lane = t & 63;
    const int l15  = lane & 15, quad = lane >> 4;
    const int wm   = wave * 32;
    const int m0   = blockIdx.y * 128,  n0 = blockIdx.x * 64;
    const int srow = lane >> 3;
    const int sch  = ((lane & 7) ^ srow) * 8;

    floatx4 acc[2][4] = {};

    for (int k0 = 0; k0 < EMB; k0 += 64) {
        {
            for (int i = 0; i < 4; ++i) {     // A: wave's 32 rows
                int rr = wave * 32 + i * 8;
                gl_lds16(&A[(size_t)(m0 + rr + srow) * EMB + k0 + sch],
                         &sA[0][0] + rr * 64);
            }
            for (int i = 0; i < 2; ++i) {     // B: wave's 16 rows
                int rr = wave * 16 + i * 8;
                gl_lds16(&B[(size_t)(n0 + rr + srow) * EMB + k0 + sch],
                         &sB[0][0] + rr * 64);
            }
        }
        __syncthreads();
        for (int ks = 0; ks < 2; ++ks) {
            const int ch = (((ks * 4) + quad) ^ (l15 & 7)) * 8;
            short8 af[2], bf[4];
            for (int i = 0; i < 2; ++i)
                af[i] = *(const short8*)&sA[wm + i * 16 + l15][ch];
            for (int j = 0; j < 4; ++j)
                bf[j] = *(const short8*)&sB[j * 16 + l15][ch];
            for (int i = 0; i < 2; ++i)
                for (int j = 0; j < 4; ++j)
                    acc[i][j] = __builtin_amdgcn_mfma_f32_16x16x32_bf16(
                        af[i], bf[j], acc[i][j], 0, 0, 0);
        }
        __syncthreads();
    }
    for (int i = 0; i < 2; ++i) {
        int row = m0 + wm + i * 16 + quad * 4;
        for (int j = 0; j < 4; ++j) {
            int col = n0 + j * 16 + l15;
            float bv = bias[col];
            for (int r = 0; r < 4; ++r)
                out[(size_t)(row + r) * EMB + col] = acc[i][j][r] + bv;
        }
    }
}

// ---------------------------------------------------------------------------
// Flash attention, transposed-score, static-max softmax.
// 256 threads = 4 waves; q-tile 64; each wave owns 16 q-rows.
// Grid: x = bh (32) -> XCD locality; y = q-tile (32). 1024 blocks = 4/CU:
// barriers hold only 4 waves, the other 12 on the CU keep issuing.
// ---------------------------------------------------------------------------
__global__ __launch_bounds__(256) void attn(
        const unsigned short* __restrict__ Q,
        const unsigned short* __restrict__ K,
        const unsigned short* __restrict__ VT,
        unsigned short* __restrict__ O) {
    __shared__ unsigned short sK [64][64];
    __shared__ unsigned short sVT[64][64];
    __shared__ unsigned short sP [64][72];
    const int t    = threadIdx.x;
    const int wave = t >> 6, lane = t & 63;
    const int l15  = lane & 15, quad = lane >> 4;
    const int bh   = blockIdx.x;                 // XCD-locality key
    const int b    = bh >> 4, h = bh & 15;
    const int q0   = blockIdx.y * 64;
    const size_t rowbase = (size_t)b * SEQ;
    const int colbase  = h * HD;
    const size_t vtbase = (size_t)bh * HD * SEQ;
    const int srow = lane >> 3;
    const int sch  = ((lane & 7) ^ srow) * 8;

    // Q fragments in registers (pre-scaled by log2e/32 in GEMM epilogue);
    // this wave's 16 q-rows: q0 + wave*16 + l15
    short8 qf[2];   // [ks]
    for (int ks = 0; ks < 2; ++ks)
        qf[ks] = *(const short8*)&Q[(rowbase + q0 + wave * 16 + l15) * EMB
                                    + colbase + ks * 32 + quad * 8];

    float l_part = 0.f;
    floatx4 o_acc[4] = {};   // [mi = d-frag]; col = q (l15)

    for (int kt = 0; kt < SEQ; kt += 64) {
        { // stage K [64 keys][64 d] and V^T [64 d][64 keys]; 4 waves x 16 rows
            for (int i = 0; i < 2; ++i) {
                int rr  = wave * 16 + i * 8;    // wave-uniform
                int row = rr + srow;
                gl_lds16(&K[(rowbase + kt + row) * EMB + colbase + sch],
                         &sK[0][0] + rr * 64);
                gl_lds16(&VT[vtbase + (size_t)row * SEQ + kt + sch],
                         &sVT[0][0] + rr * 64);
            }
        }
        __syncthreads();

        // S^T = K Q^T : s[mi] rows = keys mi*16+quad*4+r, col = q = l15
        floatx4 s[4] = {};
        for (int ks = 0; ks < 2; ++ks) {
            const int ch = (((ks * 4) + quad) ^ (l15 & 7)) * 8;
            short8 kf[4];
            for (int mi = 0; mi < 4; ++mi)
                kf[mi] = *(const short8*)&sK[mi * 16 + l15][ch];
            for (int mi = 0; mi < 4; ++mi)
                s[mi] = __builtin_amdgcn_mfma_f32_16x16x32_bf16(
                    kf[mi], qf[ks], s[mi], 0, 0, 0);
        }

        // p = exp2(s); per-lane l partial; pack to wave-private sP rows
        {
            int prow = wave * 16 + l15;
            float lp = l_part;
            for (int mi = 0; mi < 4; ++mi) {
                float p0 = __builtin_amdgcn_exp2f(s[mi][0]);
                float p1 = __builtin_amdgcn_exp2f(s[mi][1]);
                float p2 = __builtin_amdgcn_exp2f(s[mi][2]);
                float p3 = __builtin_amdgcn_exp2f(s[mi][3]);
                lp += (p0 + p1) + (p2 + p3);
                uint2 pk;
                pk.x = pk_bf16(p0, p1);
                pk.y = pk_bf16(p2, p3);
                *(uint2*)&sP[prow][mi * 16 + quad * 4] = pk;
            }
            l_part = lp;
        }

        // O^T += V^T P^T (sP rows wave-private; no barrier needed)
        for (int ks = 0; ks < 2; ++ks) {
            const int ch = (((ks * 4) + quad) ^ (l15 & 7)) * 8;
            short8 vf[4];
            for (int mi = 0; mi < 4; ++mi)
                vf[mi] = *(const short8*)&sVT[mi * 16 + l15][ch];
            short8 pf = *(const short8*)&sP[wave * 16 + l15][ks * 32 + quad * 8];
            for (int mi = 0; mi < 4; ++mi)
                o_acc[mi] = __builtin_amdgcn_mfma_f32_16x16x32_bf16(
                    vf[mi], pf, o_acc[mi], 0, 0, 0);
        }
        __syncthreads();   // protect sK/sVT for next tile
    }

    // reduce l across quads (keys were spread over quad), then normalize
    float la = l_part;
    la += __shfl_xor(la, 16, 64);
    la += __shfl_xor(la, 32, 64);
    const float inv_l = 1.0f / la;

    // bounce O^T through sP (wave-private rows), store coalesced
    {
        int prow = wave * 16 + l15;
        for (int mi = 0; mi < 4; ++mi) {
            uint2 pk;
            pk.x = pk_bf16(o_acc[mi][0] * inv_l, o_acc[mi][1] * inv_l);
            pk.y = pk_bf16(o_acc[mi][2] * inv_l, o_acc[mi][3] * inv_l);
            *(uint2*)&sP[prow][mi * 16 + quad * 4] = pk;
        }
    }
    __builtin_amdgcn_s_waitcnt(0);  // drain lgkm before wave-private re-read
    const int ql = lane >> 2, dh = (lane & 3) * 16;
    const size_t grow = rowbase + q0 + wave * 16 + ql;
    for (int i = 0; i < 2; ++i) {
        uint4 v = *(const uint4*)&sP[wave * 16 + ql][dh + i * 8];
        *(uint4*)&O[grow * EMB + colbase + dh + i * 8] = v;
    }
}

// ---------------------------------------------------------------------------
extern "C" void kernel_launch(void* const* d_in, const int* in_sizes, int n_in,
                              void* d_out, int out_size, void* d_ws, size_t ws_size,
                              hipStream_t stream) {
    const float* x  = (const float*)d_in[0];
    const float* Wq = (const float*)d_in[1];
    const float* bq = (const float*)d_in[2];
    const float* Wk = (const float*)d_in[3];
    const float* bk = (const float*)d_in[4];
    const float* Wv = (const float*)d_in[5];
    const float* bv = (const float*)d_in[6];
    const float* Wo = (const float*)d_in[7];
    const float* bo = (const float*)d_in[8];

    unsigned short* ws  = (unsigned short*)d_ws;
    unsigned short* xb  = ws;                // [4096][1024] bf16
    unsigned short* wqb = ws + 4194304;      // [1024][1024]
    unsigned short* wkb = ws + 5242880;
    unsigned short* wvb = ws + 6291456;
    unsigned short* wob = ws + 7340032;
    unsigned short* Qb  = ws + 8388608;      // [4096][1024] (pre-scaled)
    unsigned short* Kb  = ws + 12582912;     // [4096][1024]
    unsigned short* VTb = ws + 16777216;     // [32*64][2048] = V^T per (b,h)
    unsigned short* Ob  = ws + 20971520;     // attention output [4096][1024]

    convert_all<<<8192, 256, 0, stream>>>(x, Wq, Wk, Wv, Wo, ws);
    gemm_qkv<<<dim3(8, 32, 3), 256, 0, stream>>>(xb, wqb, wkb, wvb,
                                                 bq, bk, bv, Qb, Kb, VTb);
    attn<<<dim3(32, 32), 256, 0, stream>>>(Qb, Kb, VTb, Ob);
    gemm_out<<<dim3(16, 32), 256, 0, stream>>>(Ob, wob, bo, (float*)d_out);
}

// Round 10
// 181.616 us; speedup vs baseline: 1.0620x; 1.0620x over previous
//
#include <hip/hip_runtime.h>

// ---------------------------------------------------------------------------
// MultiHeadAttention: b=2, n=2048, EMB=1024, heads=16, head_dim=64
// R10: attn back to R8 shape (512 thr, q-tile 128, grid (bh=32, qt=16)) but
//      with 128 keys per barrier round: stage 2x(K,VT) tiles, one barrier,
//      compute both halves (sP wave-private), closing barrier. Halves the
//      vmcnt(0) barrier drains (64->32/block). gemm_qkv (256,3) + 128x64
//      gemm_out kept from R9 (non-attn best: 126 us).
// ---------------------------------------------------------------------------

typedef short short8  __attribute__((ext_vector_type(8)));
typedef float floatx4 __attribute__((ext_vector_type(4)));

#define SEQ   2048
#define BATCH 2
#define NH    16
#define HD    64
#define EMB   1024

// softmax_e(E/32) == softmax_2(E * log2e/32); folded into Q.
#define QSCALE 0.045084220027780106f

__device__ __forceinline__ unsigned short f32_bf16(float f) {
    unsigned int u = __float_as_uint(f);
    u += 0x7FFF + ((u >> 16) & 1);      // round-to-nearest-even
    return (unsigned short)(u >> 16);
}

// pack two floats to bf16x2 (round-to-nearest, ties-away): 2 adds + 1 perm
__device__ __forceinline__ unsigned int pk_bf16(float lo, float hi) {
    return __builtin_amdgcn_perm(__float_as_uint(hi) + 0x8000u,
                                 __float_as_uint(lo) + 0x8000u, 0x07060302u);
}

// async global->LDS, 16B per lane; LDS dest = wave-uniform base + lane*16
__device__ __forceinline__ void gl_lds16(const unsigned short* g,
                                         unsigned short* l) {
    __builtin_amdgcn_global_load_lds(
        (const __attribute__((address_space(1))) unsigned int*)g,
        (__attribute__((address_space(3))) unsigned int*)l, 16, 0, 0);
}

// ---------------------------------------------------------------------------
// fp32 -> bf16 conversion for x, Wq, Wk, Wv, Wo (laid contiguously at ws+0)
// ---------------------------------------------------------------------------
__global__ __launch_bounds__(256) void convert_all(
        const float* __restrict__ x,  const float* __restrict__ wq,
        const float* __restrict__ wk, const float* __restrict__ wv,
        const float* __restrict__ wo, unsigned short* __restrict__ dst) {
    int i = (blockIdx.x * 256 + threadIdx.x) * 4;
    const float* src; int off;
    if      (i < 4194304) { src = x;  off = 0; }
    else if (i < 5242880) { src = wq; off = 4194304; }
    else if (i < 6291456) { src = wk; off = 5242880; }
    else if (i < 7340032) { src = wv; off = 6291456; }
    else                  { src = wo; off = 7340032; }
    float4 v = *(const float4*)(src + (i - off));
    uint2 o;
    o.x = pk_bf16(v.x, v.y);
    o.y = pk_bf16(v.z, v.w);
    *(uint2*)(dst + i) = o;
}

// ---------------------------------------------------------------------------
// QKV GEMM: C[4096,1024] = A[4096,1024] * B[1024,1024]^T + bias
// 256 thr / 4 waves, 128x128 tile, global_load_lds + XOR-chunk swizzle.
// MODE 0: bf16 | MODE 1: bf16*QSCALE (Q) | MODE 2: bf16 -> VT scatter (V)
// ---------------------------------------------------------------------------
template <int MODE>
__device__ __forceinline__ void gemm_bt_core(
        unsigned short (* __restrict__ sA)[64],
        unsigned short (* __restrict__ sB)[64],
        const unsigned short* __restrict__ A,
        const unsigned short* __restrict__ B,
        const float* __restrict__ bias,
        unsigned short* __restrict__ outb) {
    const int t    = threadIdx.x;
    const int wave = t >> 6, lane = t & 63;
    const int l15  = lane & 15, quad = lane >> 4;
    const int wm   = (wave >> 1) * 64, wn = (wave & 1) * 64;
    const int m0   = blockIdx.y * 128,  n0 = blockIdx.x * 128;
    const int srow = lane >> 3;                 // 0..7
    const int sch  = ((lane & 7) ^ srow) * 8;   // swizzled source chunk

    floatx4 acc[4][4] = {};

    for (int k0 = 0; k0 < EMB; k0 += 64) {
        for (int i = 0; i < 4; ++i) {
            int rr  = wave * 32 + i * 8;        // wave-uniform row base
            int row = rr + srow;
            gl_lds16(&A[(size_t)(m0 + row) * EMB + k0 + sch], &sA[0][0] + rr * 64);
            gl_lds16(&B[(size_t)(n0 + row) * EMB + k0 + sch], &sB[0][0] + rr * 64);
        }
        __syncthreads();
        for (int ks = 0; ks < 2; ++ks) {
            const int ch = (((ks * 4) + quad) ^ (l15 & 7)) * 8;
            short8 af[4], bf[4];
            for (int i = 0; i < 4; ++i)
                af[i] = *(const short8*)&sA[wm + i * 16 + l15][ch];
            for (int j = 0; j < 4; ++j)
                bf[j] = *(const short8*)&sB[wn + j * 16 + l15][ch];
            for (int i = 0; i < 4; ++i)
                for (int j = 0; j < 4; ++j)
                    acc[i][j] = __builtin_amdgcn_mfma_f32_16x16x32_bf16(
                        af[i], bf[j], acc[i][j], 0, 0, 0);
        }
        __syncthreads();
    }
    // C/D layout: col = lane&15, row = quad*4 + reg
    if (MODE == 2) {
        // V: write transposed VT[(b*16+h)*64 + d][seq]
        for (int i = 0; i < 4; ++i) {
            int row = m0 + wm + i * 16 + quad * 4;
            int bb  = row >> 11, seq = row & 2047;
            for (int j = 0; j < 4; ++j) {
                int col = n0 + wn + j * 16 + l15;
                float bv = bias[col];
                int vtrow = (bb * 16 + (col >> 6)) * 64 + (col & 63);
                uint2 pk;
                pk.x = pk_bf16(acc[i][j][0] + bv, acc[i][j][1] + bv);
                pk.y = pk_bf16(acc[i][j][2] + bv, acc[i][j][3] + bv);
                *(uint2*)&outb[(size_t)vtrow * SEQ + seq] = pk;
            }
        }
    } else {
        const float sc2 = (MODE == 1) ? QSCALE : 1.0f;
        for (int i = 0; i < 4; ++i) {
            int row = m0 + wm + i * 16 + quad * 4;
            for (int j = 0; j < 4; ++j) {
                int col = n0 + wn + j * 16 + l15;
                float bv = bias[col];
                for (int r = 0; r < 4; ++r) {
                    float v = (acc[i][j][r] + bv) * sc2;
                    outb[(size_t)(row + r) * EMB + col] = f32_bf16(v);
                }
            }
        }
    }
}

__global__ __launch_bounds__(256, 3) void gemm_qkv(
        const unsigned short* __restrict__ xb,
        const unsigned short* __restrict__ wq,
        const unsigned short* __restrict__ wk,
        const unsigned short* __restrict__ wv,
        const float* __restrict__ bq, const float* __restrict__ bk,
        const float* __restrict__ bv,
        unsigned short* __restrict__ Q, unsigned short* __restrict__ K,
        unsigned short* __restrict__ VT) {
    __shared__ unsigned short sA[128][64];
    __shared__ unsigned short sB[128][64];
    if      (blockIdx.z == 0) gemm_bt_core<1>(sA, sB, xb, wq, bq, Q);
    else if (blockIdx.z == 1) gemm_bt_core<0>(sA, sB, xb, wk, bk, K);
    else                      gemm_bt_core<2>(sA, sB, xb, wv, bv, VT);
}

// ---------------------------------------------------------------------------
// Output GEMM (fp32 out): 128x64 tile, 256 thr / 4 waves (wave = 32m x 64n),
// grid (16,32) = 512 blocks -> 2 blocks/CU, 8 waves/CU.
// ---------------------------------------------------------------------------
__global__ __launch_bounds__(256) void gemm_out(
        const unsigned short* __restrict__ A,
        const unsigned short* __restrict__ B,
        const float* __restrict__ bias, float* __restrict__ out) {
    __shared__ unsigned short sA[128][64];
    __shared__ unsigned short sB[64][64];
    const int t    = threadIdx.x;
    const int wave = t >> 6, lane = t & 63;
    const int l15  = lane & 15, quad = lane >> 4;
    const int wm   = wave * 32;
    const int m0   = blockIdx.y * 128,  n0 = blockIdx.x * 64;
    const int srow = lane >> 3;
    const int sch  = ((lane & 7) ^ srow) * 8;

    floatx4 acc[2][4] = {};

    for (int k0 = 0; k0 < EMB; k0 += 64) {
        {
            for (int i = 0; i < 4; ++i) {     // A: wave's 32 rows
                int rr = wave * 32 + i * 8;
                gl_lds16(&A[(size_t)(m0 + rr + srow) * EMB + k0 + sch],
                         &sA[0][0] + rr * 64);
            }
            for (int i = 0; i < 2; ++i) {     // B: wave's 16 rows
                int rr = wave * 16 + i * 8;
                gl_lds16(&B[(size_t)(n0 + rr + srow) * EMB + k0 + sch],
                         &sB[0][0] + rr * 64);
            }
        }
        __syncthreads();
        for (int ks = 0; ks < 2; ++ks) {
            const int ch = (((ks * 4) + quad) ^ (l15 & 7)) * 8;
            short8 af[2], bf[4];
            for (int i = 0; i < 2; ++i)
                af[i] = *(const short8*)&sA[wm + i * 16 + l15][ch];
            for (int j = 0; j < 4; ++j)
                bf[j] = *(const short8*)&sB[j * 16 + l15][ch];
            for (int i = 0; i < 2; ++i)
                for (int j = 0; j < 4; ++j)
                    acc[i][j] = __builtin_amdgcn_mfma_f32_16x16x32_bf16(
                        af[i], bf[j], acc[i][j], 0, 0, 0);
        }
        __syncthreads();
    }
    for (int i = 0; i < 2; ++i) {
        int row = m0 + wm + i * 16 + quad * 4;
        for (int j = 0; j < 4; ++j) {
            int col = n0 + j * 16 + l15;
            float bv = bias[col];
            for (int r = 0; r < 4; ++r)
                out[(size_t)(row + r) * EMB + col] = acc[i][j][r] + bv;
        }
    }
}

// ---------------------------------------------------------------------------
// Flash attention, transposed-score, static-max softmax.
// 512 threads = 8 waves; q-tile 128; each wave owns 16 q-rows.
// Grid: x = bh (32) -> XCD locality; y = q-tile (16).
// 128 keys per barrier round: two (K,VT) tile pairs staged, ONE drain barrier,
// both halves computed (sP wave-private), one closing barrier.
// ---------------------------------------------------------------------------
__global__ __launch_bounds__(512) void attn(
        const unsigned short* __restrict__ Q,
        const unsigned short* __restrict__ K,
        const unsigned short* __restrict__ VT,
        unsigned short* __restrict__ O) {
    __shared__ unsigned short sK [2][64][64];
    __shared__ unsigned short sVT[2][64][64];
    __shared__ unsigned short sP [128][72];
    const int t    = threadIdx.x;
    const int wave = t >> 6, lane = t & 63;
    const int l15  = lane & 15, quad = lane >> 4;
    const int bh   = blockIdx.x;                 // XCD-locality key
    const int b    = bh >> 4, h = bh & 15;
    const int q0   = blockIdx.y * 128;
    const size_t rowbase = (size_t)b * SEQ;
    const int colbase  = h * HD;
    const size_t vtbase = (size_t)bh * HD * SEQ;
    const int srow = lane >> 3;
    const int sch  = ((lane & 7) ^ srow) * 8;
    const int rr   = wave * 8;          // this wave's staging slab
    const int row  = rr + srow;

    // Q fragments in registers (pre-scaled by log2e/32 in GEMM epilogue);
    // this wave's 16 q-rows: q0 + wave*16 + l15
    short8 qf[2];   // [ks]
    for (int ks = 0; ks < 2; ++ks)
        qf[ks] = *(const short8*)&Q[(rowbase + q0 + wave * 16 + l15) * EMB
                                    + colbase + ks * 32 + quad * 8];

    float l_part = 0.f;
    floatx4 o_acc[4] = {};   // [mi = d-frag]; col = q (l15)

    for (int kt = 0; kt < SEQ; kt += 128) {
        // stage both 64-key tile pairs; 8 waves x 8 rows each
        for (int hf = 0; hf < 2; ++hf) {
            const int kth = kt + hf * 64;
            gl_lds16(&K[(rowbase + kth + row) * EMB + colbase + sch],
                     &sK[hf][0][0] + rr * 64);
            gl_lds16(&VT[vtbase + (size_t)row * SEQ + kth + sch],
                     &sVT[hf][0][0] + rr * 64);
        }
        __syncthreads();   // one drain for 128 keys

        for (int hf = 0; hf < 2; ++hf) {
            // S^T = K Q^T : s[mi] rows = keys mi*16+quad*4+r, col = q = l15
            floatx4 s[4] = {};
            for (int ks = 0; ks < 2; ++ks) {
                const int ch = (((ks * 4) + quad) ^ (l15 & 7)) * 8;
                short8 kf[4];
                for (int mi = 0; mi < 4; ++mi)
                    kf[mi] = *(const short8*)&sK[hf][mi * 16 + l15][ch];
                for (int mi = 0; mi < 4; ++mi)
                    s[mi] = __builtin_amdgcn_mfma_f32_16x16x32_bf16(
                        kf[mi], qf[ks], s[mi], 0, 0, 0);
            }

            // p = exp2(s); per-lane l partial; pack to wave-private sP rows
            {
                int prow = wave * 16 + l15;
                float lp = l_part;
                for (int mi = 0; mi < 4; ++mi) {
                    float p0 = __builtin_amdgcn_exp2f(s[mi][0]);
                    float p1 = __builtin_amdgcn_exp2f(s[mi][1]);
                    float p2 = __builtin_amdgcn_exp2f(s[mi][2]);
                    float p3 = __builtin_amdgcn_exp2f(s[mi][3]);
                    lp += (p0 + p1) + (p2 + p3);
                    uint2 pk;
                    pk.x = pk_bf16(p0, p1);
                    pk.y = pk_bf16(p2, p3);
                    *(uint2*)&sP[prow][mi * 16 + quad * 4] = pk;
                }
                l_part = lp;
            }

            // O^T += V^T P^T (sP rows wave-private; no barrier needed)
            for (int ks = 0; ks < 2; ++ks) {
                const int ch = (((ks * 4) + quad) ^ (l15 & 7)) * 8;
                short8 vf[4];
                for (int mi = 0; mi < 4; ++mi)
                    vf[mi] = *(const short8*)&sVT[hf][mi * 16 + l15][ch];
                short8 pf = *(const short8*)&sP[wave * 16 + l15][ks * 32 + quad * 8];
                for (int mi = 0; mi < 4; ++mi)
                    o_acc[mi] = __builtin_amdgcn_mfma_f32_16x16x32_bf16(
                        vf[mi], pf, o_acc[mi], 0, 0, 0);
            }
        }
        __syncthreads();   // protect tile buffers for next round
    }

    // reduce l across quads (keys were spread over quad), then normalize
    float la = l_part;
    la += __shfl_xor(la, 16, 64);
    la += __shfl_xor(la, 32, 64);
    const float inv_l = 1.0f / la;

    // bounce O^T through sP (wave-private rows), store coalesced
    {
        int prow = wave * 16 + l15;
        for (int mi = 0; mi < 4; ++mi) {
            uint2 pk;
            pk.x = pk_bf16(o_acc[mi][0] * inv_l, o_acc[mi][1] * inv_l);
            pk.y = pk_bf16(o_acc[mi][2] * inv_l, o_acc[mi][3] * inv_l);
            *(uint2*)&sP[prow][mi * 16 + quad * 4] = pk;
        }
    }
    __builtin_amdgcn_s_waitcnt(0);  // drain lgkm before wave-private re-read
    const int ql = lane >> 2, dh = (lane & 3) * 16;
    const size_t grow = rowbase + q0 + wave * 16 + ql;
    for (int i = 0; i < 2; ++i) {
        uint4 v = *(const uint4*)&sP[wave * 16 + ql][dh + i * 8];
        *(uint4*)&O[grow * EMB + colbase + dh + i * 8] = v;
    }
}

// ---------------------------------------------------------------------------
extern "C" void kernel_launch(void* const* d_in, const int* in_sizes, int n_in,
                              void* d_out, int out_size, void* d_ws, size_t ws_size,
                              hipStream_t stream) {
    const float* x  = (const float*)d_in[0];
    const float* Wq = (const float*)d_in[1];
    const float* bq = (const float*)d_in[2];
    const float* Wk = (const float*)d_in[3];
    const float* bk = (const float*)d_in[4];
    const float* Wv = (const float*)d_in[5];
    const float* bv = (const float*)d_in[6];
    const float* Wo = (const float*)d_in[7];
    const float* bo = (const float*)d_in[8];

    unsigned short* ws  = (unsigned short*)d_ws;
    unsigned short* xb  = ws;                // [4096][1024] bf16
    unsigned short* wqb = ws + 4194304;      // [1024][1024]
    unsigned short* wkb = ws + 5242880;
    unsigned short* wvb = ws + 6291456;
    unsigned short* wob = ws + 7340032;
    unsigned short* Qb  = ws + 8388608;      // [4096][1024] (pre-scaled)
    unsigned short* Kb  = ws + 12582912;     // [4096][1024]
    unsigned short* VTb = ws + 16777216;     // [32*64][2048] = V^T per (b,h)
    unsigned short* Ob  = ws + 20971520;     // attention output [4096][1024]

    convert_all<<<8192, 256, 0, stream>>>(x, Wq, Wk, Wv, Wo, ws);
    gemm_qkv<<<dim3(8, 32, 3), 256, 0, stream>>>(xb, wqb, wkb, wvb,
                                                 bq, bk, bv, Qb, Kb, VTb);
    attn<<<dim3(32, 16), 512, 0, stream>>>(Qb, Kb, VTb, Ob);
    gemm_out<<<dim3(16, 32), 256, 0, stream>>>(Ob, wob, bo, (float*)d_out);
}

// Round 11
// 180.544 us; speedup vs baseline: 1.0683x; 1.0059x over previous
//
#include <hip/hip_runtime.h>

// ---------------------------------------------------------------------------
// MultiHeadAttention: b=2, n=2048, EMB=1024, heads=16, head_dim=64
// R11: composition of measured-best variants.
//  - attn: R8 verbatim (512 thr, q-tile 128, single 64-key round/barrier-pair,
//    grid (bh=32, qt=16) XCD swizzle) -- 50.4 us measured. R7 dbuf, R9 small
//    blocks, R10 128-key rounds all measured worse.
//  - gemm_qkv: (256,3), 128x128 tile -- best measured.
//  - gemm_out: 128x64 tile, 256 thr, grid (16,32) -- best measured.
// ---------------------------------------------------------------------------

typedef short short8  __attribute__((ext_vector_type(8)));
typedef float floatx4 __attribute__((ext_vector_type(4)));

#define SEQ   2048
#define BATCH 2
#define NH    16
#define HD    64
#define EMB   1024

// softmax_e(E/32) == softmax_2(E * log2e/32); folded into Q.
#define QSCALE 0.045084220027780106f

__device__ __forceinline__ unsigned short f32_bf16(float f) {
    unsigned int u = __float_as_uint(f);
    u += 0x7FFF + ((u >> 16) & 1);      // round-to-nearest-even
    return (unsigned short)(u >> 16);
}

// pack two floats to bf16x2 (round-to-nearest, ties-away): 2 adds + 1 perm
__device__ __forceinline__ unsigned int pk_bf16(float lo, float hi) {
    return __builtin_amdgcn_perm(__float_as_uint(hi) + 0x8000u,
                                 __float_as_uint(lo) + 0x8000u, 0x07060302u);
}

// async global->LDS, 16B per lane; LDS dest = wave-uniform base + lane*16
__device__ __forceinline__ void gl_lds16(const unsigned short* g,
                                         unsigned short* l) {
    __builtin_amdgcn_global_load_lds(
        (const __attribute__((address_space(1))) unsigned int*)g,
        (__attribute__((address_space(3))) unsigned int*)l, 16, 0, 0);
}

// ---------------------------------------------------------------------------
// fp32 -> bf16 conversion for x, Wq, Wk, Wv, Wo (laid contiguously at ws+0)
// ---------------------------------------------------------------------------
__global__ __launch_bounds__(256) void convert_all(
        const float* __restrict__ x,  const float* __restrict__ wq,
        const float* __restrict__ wk, const float* __restrict__ wv,
        const float* __restrict__ wo, unsigned short* __restrict__ dst) {
    int i = (blockIdx.x * 256 + threadIdx.x) * 4;
    const float* src; int off;
    if      (i < 4194304) { src = x;  off = 0; }
    else if (i < 5242880) { src = wq; off = 4194304; }
    else if (i < 6291456) { src = wk; off = 5242880; }
    else if (i < 7340032) { src = wv; off = 6291456; }
    else                  { src = wo; off = 7340032; }
    float4 v = *(const float4*)(src + (i - off));
    uint2 o;
    o.x = pk_bf16(v.x, v.y);
    o.y = pk_bf16(v.z, v.w);
    *(uint2*)(dst + i) = o;
}

// ---------------------------------------------------------------------------
// QKV GEMM: C[4096,1024] = A[4096,1024] * B[1024,1024]^T + bias
// 256 thr / 4 waves, 128x128 tile, global_load_lds + XOR-chunk swizzle.
// MODE 0: bf16 | MODE 1: bf16*QSCALE (Q) | MODE 2: bf16 -> VT scatter (V)
// ---------------------------------------------------------------------------
template <int MODE>
__device__ __forceinline__ void gemm_bt_core(
        unsigned short (* __restrict__ sA)[64],
        unsigned short (* __restrict__ sB)[64],
        const unsigned short* __restrict__ A,
        const unsigned short* __restrict__ B,
        const float* __restrict__ bias,
        unsigned short* __restrict__ outb) {
    const int t    = threadIdx.x;
    const int wave = t >> 6, lane = t & 63;
    const int l15  = lane & 15, quad = lane >> 4;
    const int wm   = (wave >> 1) * 64, wn = (wave & 1) * 64;
    const int m0   = blockIdx.y * 128,  n0 = blockIdx.x * 128;
    const int srow = lane >> 3;                 // 0..7
    const int sch  = ((lane & 7) ^ srow) * 8;   // swizzled source chunk

    floatx4 acc[4][4] = {};

    for (int k0 = 0; k0 < EMB; k0 += 64) {
        for (int i = 0; i < 4; ++i) {
            int rr  = wave * 32 + i * 8;        // wave-uniform row base
            int row = rr + srow;
            gl_lds16(&A[(size_t)(m0 + row) * EMB + k0 + sch], &sA[0][0] + rr * 64);
            gl_lds16(&B[(size_t)(n0 + row) * EMB + k0 + sch], &sB[0][0] + rr * 64);
        }
        __syncthreads();
        for (int ks = 0; ks < 2; ++ks) {
            const int ch = (((ks * 4) + quad) ^ (l15 & 7)) * 8;
            short8 af[4], bf[4];
            for (int i = 0; i < 4; ++i)
                af[i] = *(const short8*)&sA[wm + i * 16 + l15][ch];
            for (int j = 0; j < 4; ++j)
                bf[j] = *(const short8*)&sB[wn + j * 16 + l15][ch];
            for (int i = 0; i < 4; ++i)
                for (int j = 0; j < 4; ++j)
                    acc[i][j] = __builtin_amdgcn_mfma_f32_16x16x32_bf16(
                        af[i], bf[j], acc[i][j], 0, 0, 0);
        }
        __syncthreads();
    }
    // C/D layout: col = lane&15, row = quad*4 + reg
    if (MODE == 2) {
        // V: write transposed VT[(b*16+h)*64 + d][seq]
        for (int i = 0; i < 4; ++i) {
            int row = m0 + wm + i * 16 + quad * 4;
            int bb  = row >> 11, seq = row & 2047;
            for (int j = 0; j < 4; ++j) {
                int col = n0 + wn + j * 16 + l15;
                float bv = bias[col];
                int vtrow = (bb * 16 + (col >> 6)) * 64 + (col & 63);
                uint2 pk;
                pk.x = pk_bf16(acc[i][j][0] + bv, acc[i][j][1] + bv);
                pk.y = pk_bf16(acc[i][j][2] + bv, acc[i][j][3] + bv);
                *(uint2*)&outb[(size_t)vtrow * SEQ + seq] = pk;
            }
        }
    } else {
        const float sc2 = (MODE == 1) ? QSCALE : 1.0f;
        for (int i = 0; i < 4; ++i) {
            int row = m0 + wm + i * 16 + quad * 4;
            for (int j = 0; j < 4; ++j) {
                int col = n0 + wn + j * 16 + l15;
                float bv = bias[col];
                for (int r = 0; r < 4; ++r) {
                    float v = (acc[i][j][r] + bv) * sc2;
                    outb[(size_t)(row + r) * EMB + col] = f32_bf16(v);
                }
            }
        }
    }
}

__global__ __launch_bounds__(256, 3) void gemm_qkv(
        const unsigned short* __restrict__ xb,
        const unsigned short* __restrict__ wq,
        const unsigned short* __restrict__ wk,
        const unsigned short* __restrict__ wv,
        const float* __restrict__ bq, const float* __restrict__ bk,
        const float* __restrict__ bv,
        unsigned short* __restrict__ Q, unsigned short* __restrict__ K,
        unsigned short* __restrict__ VT) {
    __shared__ unsigned short sA[128][64];
    __shared__ unsigned short sB[128][64];
    if      (blockIdx.z == 0) gemm_bt_core<1>(sA, sB, xb, wq, bq, Q);
    else if (blockIdx.z == 1) gemm_bt_core<0>(sA, sB, xb, wk, bk, K);
    else                      gemm_bt_core<2>(sA, sB, xb, wv, bv, VT);
}

// ---------------------------------------------------------------------------
// Output GEMM (fp32 out): 128x64 tile, 256 thr / 4 waves (wave = 32m x 64n),
// grid (16,32) = 512 blocks -> 2 blocks/CU, 8 waves/CU.
// ---------------------------------------------------------------------------
__global__ __launch_bounds__(256) void gemm_out(
        const unsigned short* __restrict__ A,
        const unsigned short* __restrict__ B,
        const float* __restrict__ bias, float* __restrict__ out) {
    __shared__ unsigned short sA[128][64];
    __shared__ unsigned short sB[64][64];
    const int t    = threadIdx.x;
    const int wave = t >> 6, lane = t & 63;
    const int l15  = lane & 15, quad = lane >> 4;
    const int wm   = wave * 32;
    const int m0   = blockIdx.y * 128,  n0 = blockIdx.x * 64;
    const int srow = lane >> 3;
    const int sch  = ((lane & 7) ^ srow) * 8;

    floatx4 acc[2][4] = {};

    for (int k0 = 0; k0 < EMB; k0 += 64) {
        {
            for (int i = 0; i < 4; ++i) {     // A: wave's 32 rows
                int rr = wave * 32 + i * 8;
                gl_lds16(&A[(size_t)(m0 + rr + srow) * EMB + k0 + sch],
                         &sA[0][0] + rr * 64);
            }
            for (int i = 0; i < 2; ++i) {     // B: wave's 16 rows
                int rr = wave * 16 + i * 8;
                gl_lds16(&B[(size_t)(n0 + rr + srow) * EMB + k0 + sch],
                         &sB[0][0] + rr * 64);
            }
        }
        __syncthreads();
        for (int ks = 0; ks < 2; ++ks) {
            const int ch = (((ks * 4) + quad) ^ (l15 & 7)) * 8;
            short8 af[2], bf[4];
            for (int i = 0; i < 2; ++i)
                af[i] = *(const short8*)&sA[wm + i * 16 + l15][ch];
            for (int j = 0; j < 4; ++j)
                bf[j] = *(const short8*)&sB[j * 16 + l15][ch];
            for (int i = 0; i < 2; ++i)
                for (int j = 0; j < 4; ++j)
                    acc[i][j] = __builtin_amdgcn_mfma_f32_16x16x32_bf16(
                        af[i], bf[j], acc[i][j], 0, 0, 0);
        }
        __syncthreads();
    }
    for (int i = 0; i < 2; ++i) {
        int row = m0 + wm + i * 16 + quad * 4;
        for (int j = 0; j < 4; ++j) {
            int col = n0 + j * 16 + l15;
            float bv = bias[col];
            for (int r = 0; r < 4; ++r)
                out[(size_t)(row + r) * EMB + col] = acc[i][j][r] + bv;
        }
    }
}

// ---------------------------------------------------------------------------
// Flash attention (R8 verbatim), transposed-score, static-max softmax.
// 512 threads = 8 waves; q-tile 128; each wave owns 16 q-rows.
// Grid: x = bh (32) -> XCD locality; y = q-tile (16).
// ---------------------------------------------------------------------------
__global__ __launch_bounds__(512) void attn(
        const unsigned short* __restrict__ Q,
        const unsigned short* __restrict__ K,
        const unsigned short* __restrict__ VT,
        unsigned short* __restrict__ O) {
    __shared__ unsigned short sK [64][64];
    __shared__ unsigned short sVT[64][64];
    __shared__ unsigned short sP [128][72];
    const int t    = threadIdx.x;
    const int wave = t >> 6, lane = t & 63;
    const int l15  = lane & 15, quad = lane >> 4;
    const int bh   = blockIdx.x;                 // XCD-locality key
    const int b    = bh >> 4, h = bh & 15;
    const int q0   = blockIdx.y * 128;
    const size_t rowbase = (size_t)b * SEQ;
    const int colbase  = h * HD;
    const size_t vtbase = (size_t)bh * HD * SEQ;
    const int srow = lane >> 3;
    const int sch  = ((lane & 7) ^ srow) * 8;

    // Q fragments in registers (pre-scaled by log2e/32 in GEMM epilogue);
    // this wave's 16 q-rows: q0 + wave*16 + l15
    short8 qf[2];   // [ks]
    for (int ks = 0; ks < 2; ++ks)
        qf[ks] = *(const short8*)&Q[(rowbase + q0 + wave * 16 + l15) * EMB
                                    + colbase + ks * 32 + quad * 8];

    float l_part = 0.f;
    floatx4 o_acc[4] = {};   // [mi = d-frag]; col = q (l15)

    for (int kt = 0; kt < SEQ; kt += 64) {
        { // stage K [64 keys][64 d] and V^T [64 d][64 keys]; 8 waves x 8 rows
            int rr  = wave * 8;             // wave-uniform row base
            int row = rr + srow;
            gl_lds16(&K[(rowbase + kt + row) * EMB + colbase + sch],
                     &sK[0][0] + rr * 64);
            gl_lds16(&VT[vtbase + (size_t)row * SEQ + kt + sch],
                     &sVT[0][0] + rr * 64);
        }
        __syncthreads();

        // S^T = K Q^T : s[mi] rows = keys mi*16+quad*4+r, col = q = l15
        floatx4 s[4] = {};
        for (int ks = 0; ks < 2; ++ks) {
            const int ch = (((ks * 4) + quad) ^ (l15 & 7)) * 8;
            short8 kf[4];
            for (int mi = 0; mi < 4; ++mi)
                kf[mi] = *(const short8*)&sK[mi * 16 + l15][ch];
            for (int mi = 0; mi < 4; ++mi)
                s[mi] = __builtin_amdgcn_mfma_f32_16x16x32_bf16(
                    kf[mi], qf[ks], s[mi], 0, 0, 0);
        }

        // p = exp2(s); per-lane l partial; pack to wave-private sP rows
        {
            int prow = wave * 16 + l15;
            float lp = l_part;
            for (int mi = 0; mi < 4; ++mi) {
                float p0 = __builtin_amdgcn_exp2f(s[mi][0]);
                float p1 = __builtin_amdgcn_exp2f(s[mi][1]);
                float p2 = __builtin_amdgcn_exp2f(s[mi][2]);
                float p3 = __builtin_amdgcn_exp2f(s[mi][3]);
                lp += (p0 + p1) + (p2 + p3);
                uint2 pk;
                pk.x = pk_bf16(p0, p1);
                pk.y = pk_bf16(p2, p3);
                *(uint2*)&sP[prow][mi * 16 + quad * 4] = pk;
            }
            l_part = lp;
        }

        // O^T += V^T P^T (sP rows wave-private; no barrier needed)
        for (int ks = 0; ks < 2; ++ks) {
            const int ch = (((ks * 4) + quad) ^ (l15 & 7)) * 8;
            short8 vf[4];
            for (int mi = 0; mi < 4; ++mi)
                vf[mi] = *(const short8*)&sVT[mi * 16 + l15][ch];
            short8 pf = *(const short8*)&sP[wave * 16 + l15][ks * 32 + quad * 8];
            for (int mi = 0; mi < 4; ++mi)
                o_acc[mi] = __builtin_amdgcn_mfma_f32_16x16x32_bf16(
                    vf[mi], pf, o_acc[mi], 0, 0, 0);
        }
        __syncthreads();   // protect sK/sVT for next tile
    }

    // reduce l across quads (keys were spread over quad), then normalize
    float la = l_part;
    la += __shfl_xor(la, 16, 64);
    la += __shfl_xor(la, 32, 64);
    const float inv_l = 1.0f / la;

    // bounce O^T through sP (wave-private rows), store coalesced
    {
        int prow = wave * 16 + l15;
        for (int mi = 0; mi < 4; ++mi) {
            uint2 pk;
            pk.x = pk_bf16(o_acc[mi][0] * inv_l, o_acc[mi][1] * inv_l);
            pk.y = pk_bf16(o_acc[mi][2] * inv_l, o_acc[mi][3] * inv_l);
            *(uint2*)&sP[prow][mi * 16 + quad * 4] = pk;
        }
    }
    __builtin_amdgcn_s_waitcnt(0);  // drain lgkm before wave-private re-read
    const int ql = lane >> 2, dh = (lane & 3) * 16;
    const size_t grow = rowbase + q0 + wave * 16 + ql;
    for (int i = 0; i < 2; ++i) {
        uint4 v = *(const uint4*)&sP[wave * 16 + ql][dh + i * 8];
        *(uint4*)&O[grow * EMB + colbase + dh + i * 8] = v;
    }
}

// ---------------------------------------------------------------------------
extern "C" void kernel_launch(void* const* d_in, const int* in_sizes, int n_in,
                              void* d_out, int out_size, void* d_ws, size_t ws_size,
                              hipStream_t stream) {
    const float* x  = (const float*)d_in[0];
    const float* Wq = (const float*)d_in[1];
    const float* bq = (const float*)d_in[2];
    const float* Wk = (const float*)d_in[3];
    const float* bk = (const float*)d_in[4];
    const float* Wv = (const float*)d_in[5];
    const float* bv = (const float*)d_in[6];
    const float* Wo = (const float*)d_in[7];
    const float* bo = (const float*)d_in[8];

    unsigned short* ws  = (unsigned short*)d_ws;
    unsigned short* xb  = ws;                // [4096][1024] bf16
    unsigned short* wqb = ws + 4194304;      // [1024][1024]
    unsigned short* wkb = ws + 5242880;
    unsigned short* wvb = ws + 6291456;
    unsigned short* wob = ws + 7340032;
    unsigned short* Qb  = ws + 8388608;      // [4096][1024] (pre-scaled)
    unsigned short* Kb  = ws + 12582912;     // [4096][1024]
    unsigned short* VTb = ws + 16777216;     // [32*64][2048] = V^T per (b,h)
    unsigned short* Ob  = ws + 20971520;     // attention output [4096][1024]

    convert_all<<<8192, 256, 0, stream>>>(x, Wq, Wk, Wv, Wo, ws);
    gemm_qkv<<<dim3(8, 32, 3), 256, 0, stream>>>(xb, wqb, wkb, wvb,
                                                 bq, bk, bv, Qb, Kb, VTb);
    attn<<<dim3(32, 16), 512, 0, stream>>>(Qb, Kb, VTb, Ob);
    gemm_out<<<dim3(16, 32), 256, 0, stream>>>(Ob, wob, bo, (float*)d_out);
}